// Round 4
// baseline (1705.929 us; speedup 1.0000x reference)
//
#include <hip/hip_runtime.h>

#define DEVI __device__ __forceinline__

typedef __attribute__((ext_vector_type(8))) short bf16x8;
typedef __attribute__((ext_vector_type(4))) float f32x4;
typedef __attribute__((ext_vector_type(4))) unsigned short usx4;

DEVI float bf2f(unsigned short u) {
  unsigned int b = ((unsigned int)u) << 16;
  float f;
  __builtin_memcpy(&f, &b, 4);
  return f;
}
DEVI unsigned short f2bf(float f) {
  unsigned int x;
  __builtin_memcpy(&x, &f, 4);
  x += 0x7FFFu + ((x >> 16) & 1u);
  return (unsigned short)(x >> 16);
}
DEVI void gload_lds16(const void* g, void* l) {
  __builtin_amdgcn_global_load_lds((const __attribute__((address_space(1))) void*)g,
                                   (__attribute__((address_space(3))) void*)l,
                                   16, 0, 0);
}

// ---------------------------------------------------------------------------
// Weight transpose + cast: W[K][N] fp32 -> Wt[N][K] bf16
// ---------------------------------------------------------------------------
__global__ __launch_bounds__(256) void wt_kernel(const float* __restrict__ W,
                                                 unsigned short* __restrict__ Wt,
                                                 int K, int N) {
  __shared__ float t[32][33];
  const int tx = threadIdx.x & 31, ty = threadIdx.x >> 5;  // 32 x 8
  const int n0 = blockIdx.x * 32, k0 = blockIdx.y * 32;
#pragma unroll
  for (int i = 0; i < 4; ++i)
    t[ty * 4 + i][tx] = W[(size_t)(k0 + ty * 4 + i) * N + n0 + tx];
  __syncthreads();
#pragma unroll
  for (int i = 0; i < 4; ++i)
    Wt[(size_t)(n0 + ty * 4 + i) * K + k0 + tx] = f2bf(t[tx][ty * 4 + i]);
}

// ---------------------------------------------------------------------------
// LayerNorm: x fp32 [rows][768] -> bf16 out. One wave per row.
// ---------------------------------------------------------------------------
__global__ __launch_bounds__(256) void ln_kernel(const float* __restrict__ x,
                                                 const float* __restrict__ w,
                                                 const float* __restrict__ b,
                                                 unsigned short* __restrict__ o) {
  const int lane = threadIdx.x & 63;
  const int wave = threadIdx.x >> 6;
  const size_t row = (size_t)blockIdx.x * 4 + wave;
  const float* xr = x + row * 768;
  float v[12];
  float s = 0.f, sq = 0.f;
#pragma unroll
  for (int i = 0; i < 3; ++i) {
    const float4 f = *(const float4*)&xr[i * 256 + lane * 4];
    v[i * 4 + 0] = f.x; v[i * 4 + 1] = f.y; v[i * 4 + 2] = f.z; v[i * 4 + 3] = f.w;
    s += f.x + f.y + f.z + f.w;
    sq += f.x * f.x + f.y * f.y + f.z * f.z + f.w * f.w;
  }
#pragma unroll
  for (int off = 32; off > 0; off >>= 1) {
    s += __shfl_xor(s, off);
    sq += __shfl_xor(sq, off);
  }
  const float mu = s * (1.f / 768.f);
  const float rs = rsqrtf(sq * (1.f / 768.f) - mu * mu + 1e-8f);
  unsigned short* orow = o + row * 768;
#pragma unroll
  for (int i = 0; i < 3; ++i) {
    usx4 st;
#pragma unroll
    for (int j = 0; j < 4; ++j) {
      const int c = i * 256 + lane * 4 + j;
      st[j] = f2bf((v[i * 4 + j] - mu) * rs * w[c] + b[c]);
    }
    *(usx4*)&orow[i * 256 + lane * 4] = st;
  }
}

// ---------------------------------------------------------------------------
// Fused residual + LayerNorm: x2 = x + y (y bf16); write x2 fp32 and LN(x2) bf16
// ---------------------------------------------------------------------------
__global__ __launch_bounds__(256) void fuse_kernel(const float* __restrict__ x,
                                                   const unsigned short* __restrict__ y,
                                                   const float* __restrict__ w,
                                                   const float* __restrict__ b,
                                                   float* __restrict__ x2,
                                                   unsigned short* __restrict__ o) {
  const int lane = threadIdx.x & 63;
  const int wave = threadIdx.x >> 6;
  const size_t row = (size_t)blockIdx.x * 4 + wave;
  const float* xr = x + row * 768;
  const unsigned short* yr = y + row * 768;
  float* x2r = x2 + row * 768;
  float v[12];
  float s = 0.f, sq = 0.f;
#pragma unroll
  for (int i = 0; i < 3; ++i) {
    const float4 f = *(const float4*)&xr[i * 256 + lane * 4];
    const usx4 yv = *(const usx4*)&yr[i * 256 + lane * 4];
    float t0 = f.x + bf2f(yv[0]);
    float t1 = f.y + bf2f(yv[1]);
    float t2 = f.z + bf2f(yv[2]);
    float t3 = f.w + bf2f(yv[3]);
    v[i * 4 + 0] = t0; v[i * 4 + 1] = t1; v[i * 4 + 2] = t2; v[i * 4 + 3] = t3;
    s += t0 + t1 + t2 + t3;
    sq += t0 * t0 + t1 * t1 + t2 * t2 + t3 * t3;
    float4 fo; fo.x = t0; fo.y = t1; fo.z = t2; fo.w = t3;
    *(float4*)&x2r[i * 256 + lane * 4] = fo;
  }
#pragma unroll
  for (int off = 32; off > 0; off >>= 1) {
    s += __shfl_xor(s, off);
    sq += __shfl_xor(sq, off);
  }
  const float mu = s * (1.f / 768.f);
  const float rs = rsqrtf(sq * (1.f / 768.f) - mu * mu + 1e-8f);
  unsigned short* orow = o + row * 768;
#pragma unroll
  for (int i = 0; i < 3; ++i) {
    usx4 st;
#pragma unroll
    for (int j = 0; j < 4; ++j) {
      const int c = i * 256 + lane * 4 + j;
      st[j] = f2bf((v[i * 4 + j] - mu) * rs * w[c] + b[c]);
    }
    *(usx4*)&orow[i * 256 + lane * 4] = st;
  }
}

// ---------------------------------------------------------------------------
// 256x256 bf16 MFMA GEMM, 8-phase template (BK=64). 512 threads, 8 waves
// (2M x 4N, wave tile 128x64). LDS: 8 half-tile slots x 16KB (2-K-tile ring).
// Per K-tile: 4 phases of {ds_read || -> barrier -> lgkmcnt(0) -> setprio(1)
// 16 MFMA setprio(0)}; all 4 halves of tile t+1 staged at phase 0 with
// counted vmcnt(8) (never 0 mid-loop); trailing barrier per tile.
// XOR chunk swizzle, staged via pre-swizzled global source (involution).
// C = A[M,K] @ Bt[N,K]^T + bias. Epilogues 0..3.
// ---------------------------------------------------------------------------
template <int EPI>
__global__ __launch_bounds__(512, 2) void gemm256_k(
    const unsigned short* __restrict__ A, const unsigned short* __restrict__ Bt,
    const float* __restrict__ bias, int N, int K,
    unsigned short* __restrict__ O0, unsigned short* __restrict__ O1,
    unsigned short* __restrict__ O2, float* __restrict__ OF) {
  __shared__ unsigned short smem[65536];  // 128 KB, 8 slots x 8192 shorts
  const int tid = threadIdx.x;
  const int lane = tid & 63, wave = tid >> 6;
  const int wr = wave >> 2, wc = wave & 3;

  // T1: XCD-chunked block swizzle (nwg % 8 == 0 for all our grids)
  const int gx = gridDim.x;
  const int nwg = gx * gridDim.y;
  const int cpx = nwg >> 3;
  const int wgid = blockIdx.x + gx * blockIdx.y;
  const int v = (wgid & 7) * cpx + (wgid >> 3);
  const size_t n0 = (size_t)(v % gx) * 256;
  const size_t m0 = (size_t)(v / gx) * 256;

  const size_t ldgS = (size_t)K;  // row stride in shorts
  const unsigned short* Ab = A + m0 * ldgS;
  const unsigned short* Bb = Bt + n0 * ldgS;

  // staging source (pre-swizzled): phys chunk q -> row rq=q>>3, logical chunk
  // c = (q&7) ^ (rq&7). Thread covers q=tid and q=tid+512 (row +64, same c).
  const int rq0 = tid >> 3;
  const int c0s = (tid & 7) ^ (rq0 & 7);
  const size_t sOff0 = (size_t)rq0 * ldgS + (size_t)c0s * 8;
  const size_t sOff1 = sOff0 + (size_t)64 * ldgS;
  const unsigned short* srcA1 = Ab + (size_t)128 * ldgS;
  const unsigned short* srcB1 = Bb + (size_t)128 * ldgS;

  f32x4 acc[8][4];
#pragma unroll
  for (int m = 0; m < 8; ++m)
#pragma unroll
    for (int n = 0; n < 4; ++n) acc[m][n] = f32x4{0.f, 0.f, 0.f, 0.f};

  // fragment-read constants
  const int L = lane & 15, kc4 = lane >> 4;
  const int sA = wr;             // A half-slot for this wave
  const int sB = 2 + (wc >> 1);  // B half-slot for this wave
  const int co0 = ((kc4 ^ (L & 7)) << 3);        // kslot 0 chunk offset (shorts)
  const int co1 = (((4 | kc4) ^ (L & 7)) << 3);  // kslot 1

  const int nt2 = K >> 6;

#define STAGE(tt)                                                         \
  do {                                                                    \
    unsigned short* sb = &smem[((tt) & 1) * 32768];                       \
    const size_t ko = (size_t)(tt) * 64;                                  \
    gload_lds16(Ab + sOff0 + ko, sb + tid * 8);                           \
    gload_lds16(Ab + sOff1 + ko, sb + 4096 + tid * 8);                    \
    gload_lds16(srcA1 + sOff0 + ko, sb + 8192 + tid * 8);                 \
    gload_lds16(srcA1 + sOff1 + ko, sb + 8192 + 4096 + tid * 8);          \
    gload_lds16(Bb + sOff0 + ko, sb + 16384 + tid * 8);                   \
    gload_lds16(Bb + sOff1 + ko, sb + 16384 + 4096 + tid * 8);            \
    gload_lds16(srcB1 + sOff0 + ko, sb + 24576 + tid * 8);                \
    gload_lds16(srcB1 + sOff1 + ko, sb + 24576 + 4096 + tid * 8);         \
  } while (0)

#define MFMA16(AH, BH, MOFF)                                              \
  __builtin_amdgcn_s_setprio(1);                                          \
  _Pragma("unroll") for (int m = 0; m < 4; ++m)                           \
      _Pragma("unroll") for (int n = 0; n < 4; ++n)                       \
          acc[(MOFF) + m][n] =                                            \
      __builtin_amdgcn_mfma_f32_16x16x32_bf16(AH[m], BH[n],               \
                                              acc[(MOFF) + m][n], 0, 0, 0); \
  __builtin_amdgcn_s_setprio(0);                                          \
  __builtin_amdgcn_sched_barrier(0)

  STAGE(0);  // prologue

  for (int t = 0; t < nt2; ++t) {
    const unsigned short* Arow = &smem[(t & 1) * 32768 + sA * 8192] + L * 64;
    const unsigned short* Brow =
        &smem[(t & 1) * 32768 + sB * 8192] + (wc & 1) * 4096 + L * 64;
    bf16x8 aF[4], bK0[4], bK1[4];
    // -------- phase 0: kk=0, mh=0 (stage tile t+1, counted vmcnt) --------
    if (t + 1 < nt2) {
      STAGE(t + 1);
      asm volatile("s_waitcnt vmcnt(8)" ::: "memory");
    } else {
      asm volatile("s_waitcnt vmcnt(0)" ::: "memory");
    }
    __builtin_amdgcn_s_barrier();
    asm volatile("" ::: "memory");  // keep reads below the barrier
#pragma unroll
    for (int m = 0; m < 4; ++m) aF[m] = *(const bf16x8*)(Arow + m * 1024 + co0);
#pragma unroll
    for (int n = 0; n < 4; ++n) bK0[n] = *(const bf16x8*)(Brow + n * 1024 + co0);
    asm volatile("s_waitcnt lgkmcnt(0)" ::: "memory");
    __builtin_amdgcn_sched_barrier(0);
    MFMA16(aF, bK0, 0);
    // -------- phase 1: kk=1, mh=0 --------
#pragma unroll
    for (int m = 0; m < 4; ++m) aF[m] = *(const bf16x8*)(Arow + m * 1024 + co1);
#pragma unroll
    for (int n = 0; n < 4; ++n) bK1[n] = *(const bf16x8*)(Brow + n * 1024 + co1);
    asm volatile("" ::: "memory");  // pin reads before barrier
    __builtin_amdgcn_s_barrier();
    asm volatile("s_waitcnt lgkmcnt(0)" ::: "memory");
    __builtin_amdgcn_sched_barrier(0);
    MFMA16(aF, bK1, 0);
    // -------- phase 2: kk=0, mh=1 (B k0 reused from regs) --------
#pragma unroll
    for (int m = 0; m < 4; ++m)
      aF[m] = *(const bf16x8*)(Arow + 4096 + m * 1024 + co0);
    asm volatile("" ::: "memory");
    __builtin_amdgcn_s_barrier();
    asm volatile("s_waitcnt lgkmcnt(0)" ::: "memory");
    __builtin_amdgcn_sched_barrier(0);
    MFMA16(aF, bK0, 4);
    // -------- phase 3: kk=1, mh=1 (B k1 reused) --------
#pragma unroll
    for (int m = 0; m < 4; ++m)
      aF[m] = *(const bf16x8*)(Arow + 4096 + m * 1024 + co1);
    asm volatile("" ::: "memory");
    __builtin_amdgcn_s_barrier();
    asm volatile("s_waitcnt lgkmcnt(0)" ::: "memory");
    __builtin_amdgcn_sched_barrier(0);
    MFMA16(aF, bK1, 4);
    // trailing barrier: all waves' LDS reads of this parity are drained
    // (each wave drained via its lgkmcnt(0) before its MFMAs) before any
    // wave's next-iteration STAGE overwrites these slots.
    __builtin_amdgcn_s_barrier();
  }
#undef STAGE
#undef MFMA16

  const int rl = (lane >> 4) * 4;
  const int cl = lane & 15;

  if (EPI == 2) {
    // qkv epilogue. Wave's 128x64 region maps to exactly one (t,h) section.
    const int cbase = (int)n0 + wc * 64;  // multiple of 64
    const int tsec = cbase / 768;
    const int h = (cbase - tsec * 768) >> 6;
    const int rbase = (int)m0 + wr * 128;  // within one b (4096 % 256 == 0)
    const int b = rbase >> 12;
    const int s0w = rbase & 4095;
    const size_t bh = (size_t)b * 12 + h;
    if (tsec == 0) {
      // q[bh][s][d], elu+1, direct store
#pragma unroll
      for (int m = 0; m < 8; ++m)
#pragma unroll
        for (int n = 0; n < 4; ++n) {
          const int d = n * 16 + cl;
          const float bv = bias[cbase + d];
#pragma unroll
          for (int j = 0; j < 4; ++j) {
            float val = acc[m][n][j] + bv;
            val = val > 0.f ? val + 1.f : __expf(val);
            O0[(bh * 4096 + (size_t)(s0w + m * 16 + rl + j)) * 64 + d] = f2bf(val);
          }
        }
    } else {
      // k (elu+1) or v -> transpose via private 8192-short LDS slice -> [bh][d][s]
      unsigned short* dst = (tsec == 1) ? O1 : O2;
      unsigned short* wlds = &smem[wave * 8192];  // [c2:64][r2:128], XOR-swizzled
#pragma unroll
      for (int m = 0; m < 8; ++m)
#pragma unroll
        for (int n = 0; n < 4; ++n) {
          const int c2 = n * 16 + cl;
          const float bv = bias[cbase + c2];
          usx4 st;
#pragma unroll
          for (int j = 0; j < 4; ++j) {
            float val = acc[m][n][j] + bv;
            if (tsec == 1) val = val > 0.f ? val + 1.f : __expf(val);
            st[j] = f2bf(val);
          }
          const int r2 = m * 16 + rl;
          *(usx4*)&wlds[c2 * 128 + (r2 ^ ((c2 & 7) << 4))] = st;
        }
      asm volatile("s_waitcnt lgkmcnt(0)" ::: "memory");
#pragma unroll 4
      for (int dl = 0; dl < 64; ++dl) {
        const unsigned int pr =
            *(const unsigned int*)&wlds[dl * 128 + ((lane * 2) ^ ((dl & 7) << 4))];
        *(unsigned int*)&dst[(bh * 64 + dl) * 4096 + (size_t)(s0w + lane * 2)] = pr;
      }
    }
    return;
  }

  // common epilogue (EPI 0, 1, 3)
#pragma unroll
  for (int m = 0; m < 8; ++m) {
    const size_t r0 = m0 + wr * 128 + m * 16 + rl;
#pragma unroll
    for (int n = 0; n < 4; ++n) {
      const size_t c = n0 + wc * 64 + n * 16 + cl;
      const float bv = bias[c];
      if (EPI == 0) {
#pragma unroll
        for (int j = 0; j < 4; ++j) O0[(r0 + j) * (size_t)N + c] = f2bf(acc[m][n][j] + bv);
      } else if (EPI == 1) {
#pragma unroll
        for (int j = 0; j < 4; ++j) {
          float val = acc[m][n][j] + bv;
          val = 0.5f * val * (1.0f + erff(val * 0.70710678118654752f));
          O0[(r0 + j) * (size_t)N + c] = f2bf(val);
        }
      } else {  // EPI == 3: residual RMW into fp32 out
#pragma unroll
        for (int j = 0; j < 4; ++j) {
          const size_t idx = (r0 + j) * (size_t)N + c;
          OF[idx] += acc[m][n][j] + bv;
        }
      }
    }
  }
}

// ---------------------------------------------------------------------------
// kv[d][e] = sum_s k[s,d] v[s,e] per (b,h). kT/vT are [bh][64][4096] bf16.
// Writes kvT[bh][e][d] fp32. 4 waves split s-range; LDS reduce.
// ---------------------------------------------------------------------------
__global__ __launch_bounds__(256) void kv_kernel(const unsigned short* __restrict__ kT,
                                                 const unsigned short* __restrict__ vT,
                                                 float* __restrict__ kvT) {
  __shared__ float red[4 * 64 * 64];  // 64 KB
  const int tid = threadIdx.x;
  const int lane = tid & 63, wave = tid >> 6;
  const size_t bh = blockIdx.x;
  const unsigned short* kb = kT + bh * (size_t)(64 * 4096);
  const unsigned short* vb = vT + bh * (size_t)(64 * 4096);
  f32x4 acc[4][4];
#pragma unroll
  for (int m = 0; m < 4; ++m)
#pragma unroll
    for (int n = 0; n < 4; ++n) acc[m][n] = f32x4{0.f, 0.f, 0.f, 0.f};
  const int kh = (lane >> 4) * 8;
  for (int st = 0; st < 32; ++st) {
    const int s0 = wave * 1024 + st * 32 + kh;
    bf16x8 aF[4], bF[4];
#pragma unroll
    for (int m = 0; m < 4; ++m)
      aF[m] = *(const bf16x8*)&kb[(size_t)((lane & 15) + 16 * m) * 4096 + s0];
#pragma unroll
    for (int n = 0; n < 4; ++n)
      bF[n] = *(const bf16x8*)&vb[(size_t)((lane & 15) + 16 * n) * 4096 + s0];
#pragma unroll
    for (int m = 0; m < 4; ++m)
#pragma unroll
      for (int n = 0; n < 4; ++n)
        acc[m][n] = __builtin_amdgcn_mfma_f32_16x16x32_bf16(aF[m], bF[n], acc[m][n], 0, 0, 0);
  }
#pragma unroll
  for (int m = 0; m < 4; ++m)
#pragma unroll
    for (int n = 0; n < 4; ++n)
#pragma unroll
      for (int j = 0; j < 4; ++j)
        red[wave * 4096 + (m * 16 + (lane >> 4) * 4 + j) * 64 + n * 16 + (lane & 15)] =
            acc[m][n][j];
  __syncthreads();
  for (int i = 0; i < 16; ++i) {
    const int f = i * 256 + tid;
    float s = 0.f;
#pragma unroll
    for (int w = 0; w < 4; ++w) s += red[w * 4096 + f];
    const int d = f >> 6, e = f & 63;
    kvT[bh * 4096 + e * 64 + d] = s;  // transposed store
  }
}

// ---------------------------------------------------------------------------
// ksum[bh][d] = sum_s kT[bh][d][s]
// ---------------------------------------------------------------------------
__global__ __launch_bounds__(256) void ksum_kernel(const unsigned short* __restrict__ kT,
                                                   float* __restrict__ ksum) {
  __shared__ float part[256];
  const int tid = threadIdx.x;
  const int d = tid & 63, p = tid >> 6;
  const size_t bh = blockIdx.x;
  const unsigned short* kb = kT + bh * (size_t)(64 * 4096) + (size_t)d * 4096 + p * 1024;
  float s = 0.f;
  for (int i = 0; i < 128; ++i) {
    const bf16x8 v = *(const bf16x8*)&kb[i * 8];
#pragma unroll
    for (int j = 0; j < 8; ++j) s += bf2f((unsigned short)v[j]);
  }
  part[tid] = s;
  __syncthreads();
  if (tid < 64) ksum[bh * 64 + d] = part[d] + part[64 + d] + part[128 + d] + part[192 + d];
}

// ---------------------------------------------------------------------------
// attn out: out[s,e] = z_s * sum_d q[s,d] kv[d,e]; z_s = 1/sum_d q[s,d] ksum[d]
// ---------------------------------------------------------------------------
__global__ __launch_bounds__(256) void attn_out_kernel(const unsigned short* __restrict__ q,
                                                       const float* __restrict__ kvT,
                                                       const float* __restrict__ ksum,
                                                       unsigned short* __restrict__ attnout) {
  __shared__ float kvl[4096];
  __shared__ float ksl[64];
  __shared__ float zl[4 * 64];
  const int tid = threadIdx.x;
  const int lane = tid & 63, wave = tid >> 6;
  const int bh = blockIdx.x >> 2;
  const int chunk = blockIdx.x & 3;
  const int b = bh / 12, h = bh % 12;
  const float* kvb = kvT + (size_t)bh * 4096;
  for (int i = tid; i < 4096; i += 256) kvl[i] = kvb[i];
  if (tid < 64) ksl[tid] = ksum[(size_t)bh * 64 + tid];
  __syncthreads();

  const int kh = (lane >> 4) * 8;
  bf16x8 bF[4], ksF;
#pragma unroll
  for (int n = 0; n < 4; ++n) {
    bf16x8 t;
#pragma unroll
    for (int j = 0; j < 8; ++j)
      t[j] = (short)f2bf(kvl[((lane & 15) + 16 * n) * 64 + kh + j]);
    bF[n] = t;
  }
  {
    bf16x8 t;
#pragma unroll
    for (int j = 0; j < 8; ++j)
      t[j] = ((lane & 15) == 0) ? (short)f2bf(ksl[kh + j]) : (short)0;
    ksF = t;
  }
  const unsigned short* qb = q + (size_t)bh * 4096 * 64;

  for (int st = 0; st < 4; ++st) {
    const int s0 = chunk * 1024 + wave * 256 + st * 64;
    bf16x8 aF[4];
#pragma unroll
    for (int m = 0; m < 4; ++m)
      aF[m] = *(const bf16x8*)&qb[(size_t)(s0 + (lane & 15) + 16 * m) * 64 + kh];
    f32x4 acc[4][4];
    f32x4 dacc[4];
#pragma unroll
    for (int m = 0; m < 4; ++m) {
      dacc[m] = f32x4{0.f, 0.f, 0.f, 0.f};
#pragma unroll
      for (int n = 0; n < 4; ++n) acc[m][n] = f32x4{0.f, 0.f, 0.f, 0.f};
    }
#pragma unroll
    for (int m = 0; m < 4; ++m) {
#pragma unroll
      for (int n = 0; n < 4; ++n)
        acc[m][n] = __builtin_amdgcn_mfma_f32_16x16x32_bf16(aF[m], bF[n], acc[m][n], 0, 0, 0);
      dacc[m] = __builtin_amdgcn_mfma_f32_16x16x32_bf16(aF[m], ksF, dacc[m], 0, 0, 0);
    }
    if ((lane & 15) == 0) {
#pragma unroll
      for (int m = 0; m < 4; ++m)
#pragma unroll
        for (int j = 0; j < 4; ++j)
          zl[wave * 64 + m * 16 + (lane >> 4) * 4 + j] = 1.0f / dacc[m][j];
    }
    __syncthreads();
#pragma unroll
    for (int m = 0; m < 4; ++m)
#pragma unroll
      for (int n = 0; n < 4; ++n)
#pragma unroll
        for (int j = 0; j < 4; ++j) {
          const int sl = m * 16 + (lane >> 4) * 4 + j;
          const int s = s0 + sl;
          const float val = acc[m][n][j] * zl[wave * 64 + sl];
          const int e = n * 16 + (lane & 15);
          attnout[((size_t)b * 4096 + s) * 768 + h * 64 + e] = f2bf(val);
        }
    __syncthreads();
  }
}

// ---------------------------------------------------------------------------
extern "C" void kernel_launch(void* const* d_in, const int* in_sizes, int n_in,
                              void* d_out, int out_size, void* d_ws, size_t ws_size,
                              hipStream_t stream) {
  const float* x = (const float*)d_in[0];
  const float* qkv_w = (const float*)d_in[1];
  const float* qkv_b = (const float*)d_in[2];
  const float* proj_w = (const float*)d_in[3];
  const float* proj_b = (const float*)d_in[4];
  const float* fc1_w = (const float*)d_in[5];
  const float* fc1_b = (const float*)d_in[6];
  const float* fc2_w = (const float*)d_in[7];
  const float* fc2_b = (const float*)d_in[8];
  const float* ln1_w = (const float*)d_in[9];
  const float* ln1_b = (const float*)d_in[10];
  const float* ln2_w = (const float*)d_in[11];
  const float* ln2_b = (const float*)d_in[12];
  float* out = (float*)d_out;

  char* ws = (char*)d_ws;
  const size_t PL = (size_t)65536 * 768 * 2;  // one bf16 plane
  unsigned short* xn = (unsigned short*)(ws + 0 * PL);
  unsigned short* q = (unsigned short*)(ws + 1 * PL);
  unsigned short* kT = (unsigned short*)(ws + 2 * PL);
  unsigned short* vT = (unsigned short*)(ws + 3 * PL);
  unsigned short* attnout = xn;
  unsigned short* ybuf = kT;
  unsigned short* xn2 = (unsigned short*)(ws + 4 * PL);
  unsigned short* hbuf = (unsigned short*)(ws + 0 * PL);  // planes 0-3
  size_t off = 5 * PL;
  float* kvT = (float*)(ws + off); off += (size_t)192 * 4096 * 4;
  float* ksum = (float*)(ws + off); off += (size_t)192 * 64 * 4;
  unsigned short* qkvWt = (unsigned short*)(ws + off); off += (size_t)2304 * 768 * 2;
  unsigned short* projWt = (unsigned short*)(ws + off); off += (size_t)768 * 768 * 2;
  unsigned short* fc1Wt = (unsigned short*)(ws + off); off += (size_t)3072 * 768 * 2;
  unsigned short* fc2Wt = (unsigned short*)(ws + off); off += (size_t)768 * 3072 * 2;

  // 1. weight transpose+cast
  wt_kernel<<<dim3(72, 24), 256, 0, stream>>>(qkv_w, qkvWt, 768, 2304);
  wt_kernel<<<dim3(24, 24), 256, 0, stream>>>(proj_w, projWt, 768, 768);
  wt_kernel<<<dim3(96, 24), 256, 0, stream>>>(fc1_w, fc1Wt, 768, 3072);
  wt_kernel<<<dim3(24, 96), 256, 0, stream>>>(fc2_w, fc2Wt, 3072, 768);
  // 2. LN1
  ln_kernel<<<16384, 256, 0, stream>>>(x, ln1_w, ln1_b, xn);
  // 3. qkv GEMM with elu+1 + transposed k/v (LDS-transposed, coalesced)
  gemm256_k<2><<<dim3(9, 256), 512, 0, stream>>>(xn, qkvWt, qkv_b, 2304, 768, q, kT, vT, nullptr);
  // 4. ksum
  ksum_kernel<<<192, 256, 0, stream>>>(kT, ksum);
  // 5. kv
  kv_kernel<<<192, 256, 0, stream>>>(kT, vT, kvT);
  // 6. attention out
  attn_out_kernel<<<768, 256, 0, stream>>>(q, kvT, ksum, attnout);
  // 7. proj GEMM -> y
  gemm256_k<0><<<dim3(3, 256), 512, 0, stream>>>(attnout, projWt, proj_b, 768, 768, ybuf, nullptr,
                                                 nullptr, nullptr);
  // 8. residual + LN2 (x2 lives in d_out)
  fuse_kernel<<<16384, 256, 0, stream>>>(x, ybuf, ln2_w, ln2_b, out, xn2);
  // 9. fc1 + gelu
  gemm256_k<1><<<dim3(12, 256), 512, 0, stream>>>(xn2, fc1Wt, fc1_b, 3072, 768, hbuf, nullptr,
                                                  nullptr, nullptr);
  // 10. fc2 + residual RMW into out
  gemm256_k<3><<<dim3(3, 256), 512, 0, stream>>>(hbuf, fc2Wt, fc2_b, 768, 3072, nullptr, nullptr,
                                                 nullptr, out);
  (void)in_sizes; (void)n_in; (void)out_size; (void)ws_size;
}

// Round 5
// 1547.291 us; speedup vs baseline: 1.1025x; 1.1025x over previous
//
#include <hip/hip_runtime.h>

#define DEVI __device__ __forceinline__

typedef __attribute__((ext_vector_type(8))) short bf16x8;
typedef __attribute__((ext_vector_type(4))) float f32x4;
typedef __attribute__((ext_vector_type(4))) unsigned short usx4;

DEVI float bf2f(unsigned short u) {
  unsigned int b = ((unsigned int)u) << 16;
  float f;
  __builtin_memcpy(&f, &b, 4);
  return f;
}
DEVI unsigned short f2bf(float f) {
  unsigned int x;
  __builtin_memcpy(&x, &f, 4);
  x += 0x7FFFu + ((x >> 16) & 1u);
  return (unsigned short)(x >> 16);
}
DEVI void gload_lds16(const void* g, void* l) {
  __builtin_amdgcn_global_load_lds((const __attribute__((address_space(1))) void*)g,
                                   (__attribute__((address_space(3))) void*)l,
                                   16, 0, 0);
}

// ---------------------------------------------------------------------------
// Weight transpose + cast: W[K][N] fp32 -> Wt[N][K] bf16
// ---------------------------------------------------------------------------
__global__ __launch_bounds__(256) void wt_kernel(const float* __restrict__ W,
                                                 unsigned short* __restrict__ Wt,
                                                 int K, int N) {
  __shared__ float t[32][33];
  const int tx = threadIdx.x & 31, ty = threadIdx.x >> 5;  // 32 x 8
  const int n0 = blockIdx.x * 32, k0 = blockIdx.y * 32;
#pragma unroll
  for (int i = 0; i < 4; ++i)
    t[ty * 4 + i][tx] = W[(size_t)(k0 + ty * 4 + i) * N + n0 + tx];
  __syncthreads();
#pragma unroll
  for (int i = 0; i < 4; ++i)
    Wt[(size_t)(n0 + ty * 4 + i) * K + k0 + tx] = f2bf(t[tx][ty * 4 + i]);
}

// ---------------------------------------------------------------------------
// LayerNorm: x fp32 [rows][768] -> bf16 out. One wave per row.
// ---------------------------------------------------------------------------
__global__ __launch_bounds__(256) void ln_kernel(const float* __restrict__ x,
                                                 const float* __restrict__ w,
                                                 const float* __restrict__ b,
                                                 unsigned short* __restrict__ o) {
  const int lane = threadIdx.x & 63;
  const int wave = threadIdx.x >> 6;
  const size_t row = (size_t)blockIdx.x * 4 + wave;
  const float* xr = x + row * 768;
  float v[12];
  float s = 0.f, sq = 0.f;
#pragma unroll
  for (int i = 0; i < 3; ++i) {
    const float4 f = *(const float4*)&xr[i * 256 + lane * 4];
    v[i * 4 + 0] = f.x; v[i * 4 + 1] = f.y; v[i * 4 + 2] = f.z; v[i * 4 + 3] = f.w;
    s += f.x + f.y + f.z + f.w;
    sq += f.x * f.x + f.y * f.y + f.z * f.z + f.w * f.w;
  }
#pragma unroll
  for (int off = 32; off > 0; off >>= 1) {
    s += __shfl_xor(s, off);
    sq += __shfl_xor(sq, off);
  }
  const float mu = s * (1.f / 768.f);
  const float rs = rsqrtf(sq * (1.f / 768.f) - mu * mu + 1e-8f);
  unsigned short* orow = o + row * 768;
#pragma unroll
  for (int i = 0; i < 3; ++i) {
    usx4 st;
#pragma unroll
    for (int j = 0; j < 4; ++j) {
      const int c = i * 256 + lane * 4 + j;
      st[j] = f2bf((v[i * 4 + j] - mu) * rs * w[c] + b[c]);
    }
    *(usx4*)&orow[i * 256 + lane * 4] = st;
  }
}

// ---------------------------------------------------------------------------
// Fused residual + LayerNorm: x2 = x + y (y bf16); write x2 fp32 and LN(x2) bf16
// ---------------------------------------------------------------------------
__global__ __launch_bounds__(256) void fuse_kernel(const float* __restrict__ x,
                                                   const unsigned short* __restrict__ y,
                                                   const float* __restrict__ w,
                                                   const float* __restrict__ b,
                                                   float* __restrict__ x2,
                                                   unsigned short* __restrict__ o) {
  const int lane = threadIdx.x & 63;
  const int wave = threadIdx.x >> 6;
  const size_t row = (size_t)blockIdx.x * 4 + wave;
  const float* xr = x + row * 768;
  const unsigned short* yr = y + row * 768;
  float* x2r = x2 + row * 768;
  float v[12];
  float s = 0.f, sq = 0.f;
#pragma unroll
  for (int i = 0; i < 3; ++i) {
    const float4 f = *(const float4*)&xr[i * 256 + lane * 4];
    const usx4 yv = *(const usx4*)&yr[i * 256 + lane * 4];
    float t0 = f.x + bf2f(yv[0]);
    float t1 = f.y + bf2f(yv[1]);
    float t2 = f.z + bf2f(yv[2]);
    float t3 = f.w + bf2f(yv[3]);
    v[i * 4 + 0] = t0; v[i * 4 + 1] = t1; v[i * 4 + 2] = t2; v[i * 4 + 3] = t3;
    s += t0 + t1 + t2 + t3;
    sq += t0 * t0 + t1 * t1 + t2 * t2 + t3 * t3;
    float4 fo; fo.x = t0; fo.y = t1; fo.z = t2; fo.w = t3;
    *(float4*)&x2r[i * 256 + lane * 4] = fo;
  }
#pragma unroll
  for (int off = 32; off > 0; off >>= 1) {
    s += __shfl_xor(s, off);
    sq += __shfl_xor(sq, off);
  }
  const float mu = s * (1.f / 768.f);
  const float rs = rsqrtf(sq * (1.f / 768.f) - mu * mu + 1e-8f);
  unsigned short* orow = o + row * 768;
#pragma unroll
  for (int i = 0; i < 3; ++i) {
    usx4 st;
#pragma unroll
    for (int j = 0; j < 4; ++j) {
      const int c = i * 256 + lane * 4 + j;
      st[j] = f2bf((v[i * 4 + j] - mu) * rs * w[c] + b[c]);
    }
    *(usx4*)&orow[i * 256 + lane * 4] = st;
  }
}

// ---------------------------------------------------------------------------
// 128x256 bf16 MFMA GEMM. BK=32, 512 threads (8 waves, wave-tile 64x64),
// 48 KB LDS double-buffer -> 2 blocks/CU (16 waves, launch_bounds(512,4)).
// 2-barrier loop (m97 pedigree) + counted vmcnt(3) prefetch of tile t+1/t+2.
// Involution chunk swizzle on 64B rows (2-way bank alias = free).
// C = A[M,K] @ Bt[N,K]^T + bias. EPI 0: bf16 store; 1: gelu+store;
// 2: qkv split-store [bh][s][d] (elu+1 for q,k); 3: fp32 residual RMW.
// ---------------------------------------------------------------------------
template <int EPI>
__global__ __launch_bounds__(512, 4) void gemm_k(
    const unsigned short* __restrict__ A, const unsigned short* __restrict__ Bt,
    const float* __restrict__ bias, int N, int K,
    unsigned short* __restrict__ O0, unsigned short* __restrict__ O1,
    unsigned short* __restrict__ O2, float* __restrict__ OF) {
  __shared__ unsigned short sm[24576];  // A: 2x4096 @0, B: 2x8192 @8192
  const int tid = threadIdx.x;
  const int lane = tid & 63, wave = tid >> 6;
  const int wr = wave >> 2, wc = wave & 3;

  // T1: XCD-chunked block swizzle (nwg % 8 == 0 for all our grids)
  const int gx = gridDim.x;
  const int nwg = gx * gridDim.y;
  const int cpx = nwg >> 3;
  const int wgid = blockIdx.x + gx * blockIdx.y;
  const int v = (wgid & 7) * cpx + (wgid >> 3);
  const size_t n0 = (size_t)(v % gx) * 256;
  const size_t m0 = (size_t)(v / gx) * 128;

  // staging: 64B rows = 4 chunks of 16B. phys chunk pc at row r holds logical
  // chunk c = pc ^ f(r), f(r) = (r ^ (r>>2)) & 3 (involution both sides).
  const int rA = tid >> 2;                       // 0..127
  const int cA = (tid & 3) ^ ((rA ^ (rA >> 2)) & 3);
  const unsigned short* srcA = A + (m0 + rA) * (size_t)K + cA * 8;
  const unsigned short* srcB0 = Bt + (n0 + rA) * (size_t)K + cA * 8;
  const unsigned short* srcB1 = srcB0 + (size_t)128 * K;  // f(r+128)==f(r)

  unsigned short* smA = sm;
  unsigned short* smB = sm + 8192;

  f32x4 acc[4][4];
#pragma unroll
  for (int m = 0; m < 4; ++m)
#pragma unroll
    for (int n = 0; n < 4; ++n) acc[m][n] = f32x4{0.f, 0.f, 0.f, 0.f};

  // fragment reads: row = (base + m*16 + L) -> f(row) = fL (indep of m)
  const int L = lane & 15, kc4 = lane >> 4;
  const int fL = (L ^ (L >> 2)) & 3;
  const int aoff = (wr * 64 + L) * 32 + ((kc4 ^ fL) << 3);
  const int boff = (wc * 64 + L) * 32 + ((kc4 ^ fL) << 3);

  const int nt = K >> 5;

#define STAGE(tt)                                              \
  do {                                                         \
    const int p_ = (tt) & 1;                                   \
    const size_t ko_ = (size_t)(tt) * 32;                      \
    gload_lds16(srcA + ko_, smA + p_ * 4096 + tid * 8);        \
    gload_lds16(srcB0 + ko_, smB + p_ * 8192 + tid * 8);       \
    gload_lds16(srcB1 + ko_, smB + p_ * 8192 + 4096 + tid * 8);\
  } while (0)

  STAGE(0);
  STAGE(1);

  for (int t = 0; t < nt; ++t) {
    if (t + 1 < nt)
      asm volatile("s_waitcnt vmcnt(3)" ::: "memory");
    else
      asm volatile("s_waitcnt vmcnt(0)" ::: "memory");
    __builtin_amdgcn_s_barrier();  // buf[t&1] staged; prior reads all done
    const unsigned short* Abase = smA + (t & 1) * 4096 + aoff;
    const unsigned short* Bbase = smB + (t & 1) * 8192 + boff;
    bf16x8 aF[4], bF[4];
#pragma unroll
    for (int m = 0; m < 4; ++m) aF[m] = *(const bf16x8*)(Abase + m * 512);
#pragma unroll
    for (int n = 0; n < 4; ++n) bF[n] = *(const bf16x8*)(Bbase + n * 512);
    asm volatile("s_waitcnt lgkmcnt(0)" ::: "memory");
    __builtin_amdgcn_s_barrier();  // all waves' reads of buf[t&1] drained
    if (t + 2 < nt) STAGE(t + 2);  // safe to overwrite buf[t&1]
    __builtin_amdgcn_s_setprio(1);
#pragma unroll
    for (int m = 0; m < 4; ++m)
#pragma unroll
      for (int n = 0; n < 4; ++n)
        acc[m][n] = __builtin_amdgcn_mfma_f32_16x16x32_bf16(aF[m], bF[n], acc[m][n], 0, 0, 0);
    __builtin_amdgcn_s_setprio(0);
  }
#undef STAGE

  const int rl = (lane >> 4) * 4;
  const int cl = lane & 15;

  if (EPI == 2) {
    // qkv: wave's 64x64 region is one (tsec, h) section; store [bh][s][d].
    const int cbase = (int)n0 + wc * 64;
    const int tsec = cbase / 768;
    const int h = (cbase - tsec * 768) >> 6;
    const int rbase = (int)m0 + wr * 64;
    const int b = rbase >> 12;
    const int s0w = rbase & 4095;
    const size_t bh = (size_t)b * 12 + h;
    unsigned short* dst = (tsec == 0) ? O0 : (tsec == 1 ? O1 : O2);
#pragma unroll
    for (int m = 0; m < 4; ++m)
#pragma unroll
      for (int n = 0; n < 4; ++n) {
        const int d = n * 16 + cl;
        const float bv = bias[cbase + d];
#pragma unroll
        for (int j = 0; j < 4; ++j) {
          float val = acc[m][n][j] + bv;
          if (tsec < 2) val = val > 0.f ? val + 1.f : __expf(val);
          dst[(bh * 4096 + (size_t)(s0w + m * 16 + rl + j)) * 64 + d] = f2bf(val);
        }
      }
    return;
  }

  // common epilogue (EPI 0, 1, 3)
#pragma unroll
  for (int m = 0; m < 4; ++m) {
    const size_t r0 = m0 + wr * 64 + m * 16 + rl;
#pragma unroll
    for (int n = 0; n < 4; ++n) {
      const size_t c = n0 + wc * 64 + n * 16 + cl;
      const float bv = bias[c];
      if (EPI == 0) {
#pragma unroll
        for (int j = 0; j < 4; ++j) O0[(r0 + j) * (size_t)N + c] = f2bf(acc[m][n][j] + bv);
      } else if (EPI == 1) {
#pragma unroll
        for (int j = 0; j < 4; ++j) {
          float val = acc[m][n][j] + bv;
          val = 0.5f * val * (1.0f + erff(val * 0.70710678118654752f));
          O0[(r0 + j) * (size_t)N + c] = f2bf(val);
        }
      } else {  // EPI == 3: residual RMW into fp32 out
#pragma unroll
        for (int j = 0; j < 4; ++j) {
          const size_t idx = (r0 + j) * (size_t)N + c;
          OF[idx] += acc[m][n][j] + bv;
        }
      }
    }
  }
}

// ---------------------------------------------------------------------------
// kv + ksum fused. k,v are [bh][s][d] bf16 (d=64, s=4096).
// Per bh: stage 128-s tiles transposed+swizzled into LDS, MFMA kv[d][e],
// accumulate ksum[d]. Writes kvT[bh][e][d] fp32 and ksum[bh][d].
// LDS rows: R = d*4 + (s>>5), 32 shorts/row, chunk swizzle f(R)=(R^(R>>2))&3.
// ---------------------------------------------------------------------------
__global__ __launch_bounds__(256) void kv_kernel(const unsigned short* __restrict__ k,
                                                 const unsigned short* __restrict__ v,
                                                 float* __restrict__ kvT,
                                                 float* __restrict__ ksum) {
  __shared__ unsigned short kl[8192];  // 16 KB
  __shared__ unsigned short vl[8192];  // 16 KB
  __shared__ float red[256];
  const int tid = threadIdx.x, lane = tid & 63, wave = tid >> 6;
  const size_t bh = blockIdx.x;
  const unsigned short* kb = k + bh * (size_t)(4096 * 64);
  const unsigned short* vb = v + bh * (size_t)(4096 * 64);
  f32x4 acc[4];
#pragma unroll
  for (int n = 0; n < 4; ++n) acc[n] = f32x4{0.f, 0.f, 0.f, 0.f};
  float ks = 0.f;

  const int r = tid >> 1;       // s-row 0..127
  const int hf = tid & 1;       // d half
  const int c4 = r >> 5;        // s>>5 quarter
  const int scw = (r >> 3) & 3; // write sub-chunk
  int wofs[4];
#pragma unroll
  for (int dd = 0; dd < 4; ++dd)
    wofs[dd] = c4 * 32 + ((scw ^ ((c4 ^ dd) & 3)) << 3) + (r & 7);

  const int L = lane & 15, kc4 = lane >> 4;
  const int dA = wave * 16 + L;
  const int dq = tid & 63, q4 = tid >> 6;
  const int Fks = (q4 ^ dq) & 3;
  const int ksbase = (dq * 4 + q4) * 32;

  for (int st = 0; st < 32; ++st) {
    const int s0 = st * 128;
    __syncthreads();  // prior tile's reads done before overwrite
    {
      const unsigned short* krow = kb + (size_t)(s0 + r) * 64 + hf * 32;
      const unsigned short* vrow = vb + (size_t)(s0 + r) * 64 + hf * 32;
      bf16x8 kk[4], vv[4];
#pragma unroll
      for (int g = 0; g < 4; ++g) {
        kk[g] = *(const bf16x8*)(krow + g * 8);
        vv[g] = *(const bf16x8*)(vrow + g * 8);
      }
#pragma unroll
      for (int g = 0; g < 4; ++g)
#pragma unroll
        for (int i = 0; i < 8; ++i) {
          const int d = hf * 32 + g * 8 + i;
          const int a = d * 128 + wofs[d & 3];
          kl[a] = (unsigned short)kk[g][i];
          vl[a] = (unsigned short)vv[g][i];
        }
    }
    __syncthreads();
    // ksum partial
#pragma unroll
    for (int scc = 0; scc < 4; ++scc) {
      const bf16x8 t8 = *(const bf16x8*)&kl[ksbase + ((scc ^ Fks) << 3)];
#pragma unroll
      for (int i = 0; i < 8; ++i) ks += bf2f((unsigned short)t8[i]);
    }
    // MFMA: D[d][e] += sum_s k[s,d] v[s,e]
#pragma unroll
    for (int ksl = 0; ksl < 4; ++ksl) {
      const int physA = kc4 ^ ((ksl ^ dA) & 3);
      const bf16x8 aF = *(const bf16x8*)&kl[(dA * 4 + ksl) * 32 + physA * 8];
#pragma unroll
      for (int n = 0; n < 4; ++n) {
        const int e = n * 16 + L;
        const int physB = kc4 ^ ((ksl ^ e) & 3);
        const bf16x8 bF = *(const bf16x8*)&vl[(e * 4 + ksl) * 32 + physB * 8];
        acc[n] = __builtin_amdgcn_mfma_f32_16x16x32_bf16(aF, bF, acc[n], 0, 0, 0);
      }
    }
  }
  red[tid] = ks;
  __syncthreads();
  if (tid < 64) ksum[bh * 64 + tid] = red[tid] + red[64 + tid] + red[128 + tid] + red[192 + tid];
  // D row = d = wave*16 + (lane>>4)*4 + j ; col = e = n*16 + (lane&15)
#pragma unroll
  for (int n = 0; n < 4; ++n)
#pragma unroll
    for (int j = 0; j < 4; ++j) {
      const int d = wave * 16 + (lane >> 4) * 4 + j;
      const int e = n * 16 + (lane & 15);
      kvT[bh * 4096 + e * 64 + d] = acc[n][j];
    }
}

// ---------------------------------------------------------------------------
// attn out: out[s,e] = z_s * sum_d q[s,d] kv[d,e]; z_s = 1/sum_d q[s,d] ksum[d]
// ---------------------------------------------------------------------------
__global__ __launch_bounds__(256) void attn_out_kernel(const unsigned short* __restrict__ q,
                                                       const float* __restrict__ kvT,
                                                       const float* __restrict__ ksum,
                                                       unsigned short* __restrict__ attnout) {
  __shared__ float kvl[4096];
  __shared__ float ksl[64];
  __shared__ float zl[4 * 64];
  const int tid = threadIdx.x;
  const int lane = tid & 63, wave = tid >> 6;
  const int bh = blockIdx.x >> 2;
  const int chunk = blockIdx.x & 3;
  const int b = bh / 12, h = bh % 12;
  const float* kvb = kvT + (size_t)bh * 4096;
  for (int i = tid; i < 4096; i += 256) kvl[i] = kvb[i];
  if (tid < 64) ksl[tid] = ksum[(size_t)bh * 64 + tid];
  __syncthreads();

  const int kh = (lane >> 4) * 8;
  bf16x8 bF[4], ksF;
#pragma unroll
  for (int n = 0; n < 4; ++n) {
    bf16x8 t;
#pragma unroll
    for (int j = 0; j < 8; ++j)
      t[j] = (short)f2bf(kvl[((lane & 15) + 16 * n) * 64 + kh + j]);
    bF[n] = t;
  }
  {
    bf16x8 t;
#pragma unroll
    for (int j = 0; j < 8; ++j)
      t[j] = ((lane & 15) == 0) ? (short)f2bf(ksl[kh + j]) : (short)0;
    ksF = t;
  }
  const unsigned short* qb = q + (size_t)bh * 4096 * 64;

  for (int st = 0; st < 4; ++st) {
    const int s0 = chunk * 1024 + wave * 256 + st * 64;
    bf16x8 aF[4];
#pragma unroll
    for (int m = 0; m < 4; ++m)
      aF[m] = *(const bf16x8*)&qb[(size_t)(s0 + (lane & 15) + 16 * m) * 64 + kh];
    f32x4 acc[4][4];
    f32x4 dacc[4];
#pragma unroll
    for (int m = 0; m < 4; ++m) {
      dacc[m] = f32x4{0.f, 0.f, 0.f, 0.f};
#pragma unroll
      for (int n = 0; n < 4; ++n) acc[m][n] = f32x4{0.f, 0.f, 0.f, 0.f};
    }
#pragma unroll
    for (int m = 0; m < 4; ++m) {
#pragma unroll
      for (int n = 0; n < 4; ++n)
        acc[m][n] = __builtin_amdgcn_mfma_f32_16x16x32_bf16(aF[m], bF[n], acc[m][n], 0, 0, 0);
      dacc[m] = __builtin_amdgcn_mfma_f32_16x16x32_bf16(aF[m], ksF, dacc[m], 0, 0, 0);
    }
    if ((lane & 15) == 0) {
#pragma unroll
      for (int m = 0; m < 4; ++m)
#pragma unroll
        for (int j = 0; j < 4; ++j)
          zl[wave * 64 + m * 16 + (lane >> 4) * 4 + j] = 1.0f / dacc[m][j];
    }
    __syncthreads();
#pragma unroll
    for (int m = 0; m < 4; ++m)
#pragma unroll
      for (int n = 0; n < 4; ++n)
#pragma unroll
        for (int j = 0; j < 4; ++j) {
          const int sl = m * 16 + (lane >> 4) * 4 + j;
          const int s = s0 + sl;
          const float val = acc[m][n][j] * zl[wave * 64 + sl];
          const int e = n * 16 + (lane & 15);
          attnout[((size_t)b * 4096 + s) * 768 + h * 64 + e] = f2bf(val);
        }
    __syncthreads();
  }
}

// ---------------------------------------------------------------------------
extern "C" void kernel_launch(void* const* d_in, const int* in_sizes, int n_in,
                              void* d_out, int out_size, void* d_ws, size_t ws_size,
                              hipStream_t stream) {
  const float* x = (const float*)d_in[0];
  const float* qkv_w = (const float*)d_in[1];
  const float* qkv_b = (const float*)d_in[2];
  const float* proj_w = (const float*)d_in[3];
  const float* proj_b = (const float*)d_in[4];
  const float* fc1_w = (const float*)d_in[5];
  const float* fc1_b = (const float*)d_in[6];
  const float* fc2_w = (const float*)d_in[7];
  const float* fc2_b = (const float*)d_in[8];
  const float* ln1_w = (const float*)d_in[9];
  const float* ln1_b = (const float*)d_in[10];
  const float* ln2_w = (const float*)d_in[11];
  const float* ln2_b = (const float*)d_in[12];
  float* out = (float*)d_out;

  char* ws = (char*)d_ws;
  const size_t PL = (size_t)65536 * 768 * 2;  // one bf16 plane
  unsigned short* xn = (unsigned short*)(ws + 0 * PL);
  unsigned short* q = (unsigned short*)(ws + 1 * PL);
  unsigned short* kbuf = (unsigned short*)(ws + 2 * PL);
  unsigned short* vbuf = (unsigned short*)(ws + 3 * PL);
  unsigned short* attnout = xn;
  unsigned short* ybuf = kbuf;
  unsigned short* xn2 = (unsigned short*)(ws + 4 * PL);
  unsigned short* hbuf = (unsigned short*)(ws + 0 * PL);  // planes 0-3
  size_t off = 5 * PL;
  float* kvT = (float*)(ws + off); off += (size_t)192 * 4096 * 4;
  float* ksum = (float*)(ws + off); off += (size_t)192 * 64 * 4;
  unsigned short* qkvWt = (unsigned short*)(ws + off); off += (size_t)2304 * 768 * 2;
  unsigned short* projWt = (unsigned short*)(ws + off); off += (size_t)768 * 768 * 2;
  unsigned short* fc1Wt = (unsigned short*)(ws + off); off += (size_t)3072 * 768 * 2;
  unsigned short* fc2Wt = (unsigned short*)(ws + off); off += (size_t)768 * 3072 * 2;

  // 1. weight transpose+cast
  wt_kernel<<<dim3(72, 24), 256, 0, stream>>>(qkv_w, qkvWt, 768, 2304);
  wt_kernel<<<dim3(24, 24), 256, 0, stream>>>(proj_w, projWt, 768, 768);
  wt_kernel<<<dim3(96, 24), 256, 0, stream>>>(fc1_w, fc1Wt, 768, 3072);
  wt_kernel<<<dim3(24, 96), 256, 0, stream>>>(fc2_w, fc2Wt, 3072, 768);
  // 2. LN1
  ln_kernel<<<16384, 256, 0, stream>>>(x, ln1_w, ln1_b, xn);
  // 3. qkv GEMM: q,k (elu+1), v all stored [bh][s][d]
  gemm_k<2><<<dim3(9, 512), 512, 0, stream>>>(xn, qkvWt, qkv_b, 2304, 768, q, kbuf, vbuf, nullptr);
  // 4. kv + ksum (transpose inside)
  kv_kernel<<<192, 256, 0, stream>>>(kbuf, vbuf, kvT, ksum);
  // 5. attention out
  attn_out_kernel<<<768, 256, 0, stream>>>(q, kvT, ksum, attnout);
  // 6. proj GEMM -> y
  gemm_k<0><<<dim3(3, 512), 512, 0, stream>>>(attnout, projWt, proj_b, 768, 768, ybuf, nullptr,
                                              nullptr, nullptr);
  // 7. residual + LN2 (x2 lives in d_out)
  fuse_kernel<<<16384, 256, 0, stream>>>(x, ybuf, ln2_w, ln2_b, out, xn2);
  // 8. fc1 + gelu
  gemm_k<1><<<dim3(12, 512), 512, 0, stream>>>(xn2, fc1Wt, fc1_b, 3072, 768, hbuf, nullptr,
                                               nullptr, nullptr);
  // 9. fc2 + residual RMW into out
  gemm_k<3><<<dim3(3, 512), 512, 0, stream>>>(hbuf, fc2Wt, fc2_b, 768, 3072, nullptr, nullptr,
                                              nullptr, out);
  (void)in_sizes; (void)n_in; (void)out_size; (void)ws_size;
}